// Round 13
// baseline (114.466 us; speedup 1.0000x reference)
//
#include <hip/hip_runtime.h>
#include <hip/hip_bf16.h>

#define DIM 768
#define EPS 1e-8f
#define MAXB 1024
#define MAXVEC (MAXB * 12)

// ---------------- K0: scan lens -> offsets + vector->example-id maps -------
__global__ __launch_bounds__(1024) void scan_kernel(
    const int* __restrict__ p_lens, const int* __restrict__ n_lens,
    int* __restrict__ p_off, int* __restrict__ n_off,
    int* __restrict__ aid_p, int* __restrict__ aid_n, int bs)
{
    __shared__ int sp[MAXB], sn[MAXB];
    const int tid = threadIdx.x;
    const int p = (tid < bs) ? p_lens[tid] : 0;
    const int n = (tid < bs) ? n_lens[tid] : 0;
    sp[tid] = p; sn[tid] = n;
    __syncthreads();
    for (int off = 1; off < MAXB; off <<= 1) {     // Hillis-Steele inclusive
        int vp = (tid >= off) ? sp[tid - off] : 0;
        int vn = (tid >= off) ? sn[tid - off] : 0;
        __syncthreads();
        sp[tid] += vp; sn[tid] += vn;
        __syncthreads();
    }
    if (tid < bs) {
        const int poe = sp[tid] - p;               // exclusive
        const int noe = sn[tid] - n;
        p_off[tid] = poe;
        n_off[tid] = noe;
        for (int j = 0; j < p; ++j) aid_p[poe + j] = tid;
        for (int j = 0; j < n; ++j) aid_n[noe + j] = tid;
    }
}

// ---------------- K1: one wave per vector, barrier-free cosine --------------
// Vector loads issue first (address independent of everything); aid lookup
// (broadcast L2 load) -> anchor loads overlap the HBM wait. One 3-var
// butterfly, lane 0 stores the cosine. Max load-issue density, no scan.
__global__ __launch_bounds__(512) void cosine_kernel(
    const float* __restrict__ anchor, const float* __restrict__ positive,
    const float* __restrict__ negative,
    const int* __restrict__ aid_p, const int* __restrict__ aid_n,
    float* __restrict__ cosv, int P, int N)
{
    const int wave = threadIdx.x >> 6;
    const int lane = threadIdx.x & 63;
    const int vid = blockIdx.x * 8 + wave;
    if (vid >= P + N) return;                      // wave-uniform exit
    const bool isPos = (vid < P);

    const float* x = isPos ? positive + (size_t)vid * DIM
                           : negative + (size_t)(vid - P) * DIM;
    const float4* x4 = (const float4*)x;
    const float4 xa = x4[lane];
    const float4 xb = x4[lane + 64];
    const float4 xc = x4[lane + 128];

    const int e = isPos ? aid_p[vid] : aid_n[vid - P];   // broadcast load
    const float4* a4 = (const float4*)(anchor + (size_t)e * DIM);
    const float4 aa = a4[lane];
    const float4 ab = a4[lane + 64];
    const float4 ac = a4[lane + 128];

    float dot = aa.x*xa.x + aa.y*xa.y + aa.z*xa.z + aa.w*xa.w
              + ab.x*xb.x + ab.y*xb.y + ab.z*xb.z + ab.w*xb.w
              + ac.x*xc.x + ac.y*xc.y + ac.z*xc.z + ac.w*xc.w;
    float nx  = xa.x*xa.x + xa.y*xa.y + xa.z*xa.z + xa.w*xa.w
              + xb.x*xb.x + xb.y*xb.y + xb.z*xb.z + xb.w*xb.w
              + xc.x*xc.x + xc.y*xc.y + xc.z*xc.z + xc.w*xc.w;
    float asq = aa.x*aa.x + aa.y*aa.y + aa.z*aa.z + aa.w*aa.w
              + ab.x*ab.x + ab.y*ab.y + ab.z*ab.z + ab.w*ab.w
              + ac.x*ac.x + ac.y*ac.y + ac.z*ac.z + ac.w*ac.w;

    #pragma unroll
    for (int s = 32; s > 0; s >>= 1) {
        dot += __shfl_xor(dot, s);
        nx  += __shfl_xor(nx, s);
        asq += __shfl_xor(asq, s);
    }
    if (lane == 0)
        cosv[vid] = dot / fmaxf(sqrtf(asq) * sqrtf(nx), EPS);
}

// ---------------- K2: per-example pair hinges + global mean -----------------
__global__ __launch_bounds__(1024) void pairsum_kernel(
    const int* __restrict__ p_lens, const int* __restrict__ n_lens,
    const int* __restrict__ p_off, const int* __restrict__ n_off,
    const float* __restrict__ cosv, float* __restrict__ out, int P, int bs)
{
    const int tid = threadIdx.x;
    const int wave = tid >> 6;
    const int lane = tid & 63;
    __shared__ float sw[16];
    __shared__ int   si[16];

    float s = 0.0f;
    int   tp = 0;
    if (tid < bs) {
        const int pl = p_lens[tid], nl = n_lens[tid];
        const float* cp = cosv + p_off[tid];
        const float* cn = cosv + P + n_off[tid];
        tp = pl * nl;
        for (int j = 0; j < pl; ++j) {
            const float cap = cp[j];
            for (int k = 0; k < nl; ++k)
                s += fmaxf(cn[k] - cap + 1.0f, 0.0f);   // = d_ap - d_an + 1
        }
    }
    #pragma unroll
    for (int sh = 32; sh > 0; sh >>= 1) {
        s  += __shfl_xor(s, sh);
        tp += __shfl_xor(tp, sh);
    }
    if (lane == 0) { sw[wave] = s; si[wave] = tp; }
    __syncthreads();
    if (tid == 0) {
        float S = 0.0f; int T = 0;
        #pragma unroll
        for (int w = 0; w < 16; ++w) { S += sw[w]; T += si[w]; }
        *out = S / (float)T;
    }
}

extern "C" void kernel_launch(void* const* d_in, const int* in_sizes, int n_in,
                              void* d_out, int out_size, void* d_ws, size_t ws_size,
                              hipStream_t stream) {
    const float* anchor   = (const float*)d_in[0];
    const float* positive = (const float*)d_in[1];
    const float* negative = (const float*)d_in[2];
    const int*   p_lens   = (const int*)d_in[3];
    const int*   n_lens   = (const int*)d_in[4];
    float* out = (float*)d_out;

    const int bs = in_sizes[3];           // 1024
    const int P  = in_sizes[1] / DIM;     // total positive vectors
    const int N  = in_sizes[2] / DIM;     // total negative vectors

    int* p_off = (int*)d_ws;
    int* n_off = p_off + MAXB;
    int* aid_p = n_off + MAXB;
    int* aid_n = aid_p + MAXVEC;
    float* cosv = (float*)(aid_n + MAXVEC);

    scan_kernel<<<1, 1024, 0, stream>>>(p_lens, n_lens, p_off, n_off,
                                        aid_p, aid_n, bs);
    const int nvec = P + N;
    cosine_kernel<<<(nvec + 7) / 8, 512, 0, stream>>>(anchor, positive, negative,
                                                      aid_p, aid_n, cosv, P, N);
    pairsum_kernel<<<1, 1024, 0, stream>>>(p_lens, n_lens, p_off, n_off,
                                           cosv, out, P, bs);
}

// Round 15
// 110.712 us; speedup vs baseline: 1.0339x; 1.0339x over previous
//
#include <hip/hip_runtime.h>
#include <hip/hip_bf16.h>

#define DIM 768
#define EPS 1e-8f

// ---------------- K1: one wave per vector, in-wave searchsorted -------------
// Each wave owns one pos/neg vector. The 3 float4 vector loads issue first
// (address independent of everything). While they are in flight the wave
// derives its example id e: lane l covers lens[16l..16l+16), 6-shuffle
// inclusive prefix across lanes, unrolled in-chunk locate, max-reduce.
// Then anchor loads (L2/L3-hot), FMAs, one 3-var butterfly, store cosine.
__global__ __launch_bounds__(512) void cosine_kernel(
    const float* __restrict__ anchor, const float* __restrict__ positive,
    const float* __restrict__ negative,
    const int* __restrict__ p_lens, const int* __restrict__ n_lens,
    float* __restrict__ cosv, int P, int N, int bs)
{
    const int wave = threadIdx.x >> 6;
    const int lane = threadIdx.x & 63;
    const int vid0 = blockIdx.x * 8 + wave;
    if (vid0 >= P + N) return;                 // wave-uniform exit
    const bool isPos = (vid0 < P);
    const int vid = isPos ? vid0 : vid0 - P;   // index within its segment

    // ---- issue vector loads immediately ----
    const float* x = isPos ? positive + (size_t)vid * DIM
                           : negative + (size_t)vid * DIM;
    const float4* x4 = (const float4*)x;
    const float4 xa = x4[lane];
    const float4 xb = x4[lane + 64];
    const float4 xc = x4[lane + 128];

    // ---- in-wave searchsorted over the right lens array ----
    const int* lens = isPos ? p_lens : n_lens;
    const int base = lane << 4;                // 16 entries per lane
    int vals[16];
    if (base + 16 <= bs) {
        const int4* L4 = (const int4*)(lens + base);
        const int4 A = L4[0], B = L4[1], C = L4[2], D = L4[3];
        vals[0]=A.x; vals[1]=A.y; vals[2]=A.z; vals[3]=A.w;
        vals[4]=B.x; vals[5]=B.y; vals[6]=B.z; vals[7]=B.w;
        vals[8]=C.x; vals[9]=C.y; vals[10]=C.z; vals[11]=C.w;
        vals[12]=D.x; vals[13]=D.y; vals[14]=D.z; vals[15]=D.w;
    } else {
        #pragma unroll
        for (int j = 0; j < 16; ++j)
            vals[j] = (base + j < bs) ? lens[base + j] : 0;
    }
    int chunk = 0;
    #pragma unroll
    for (int j = 0; j < 16; ++j) chunk += vals[j];
    int incl = chunk;
    #pragma unroll
    for (int s = 1; s < 64; s <<= 1) {
        int t = __shfl_up(incl, s);
        if (lane >= s) incl += t;
    }
    int acc = incl - chunk;                    // exclusive prefix at chunk start
    int e_loc = -1;
    #pragma unroll
    for (int j = 0; j < 16; ++j) {
        if (vid >= acc && vid < acc + vals[j]) e_loc = base + j;
        acc += vals[j];
    }
    #pragma unroll
    for (int s = 32; s > 0; s >>= 1) e_loc = max(e_loc, __shfl_xor(e_loc, s));
    const int e = e_loc;

    // ---- anchor loads (cache-hot: 3 MB total, re-read ~13x) ----
    const float4* a4 = (const float4*)(anchor + (size_t)e * DIM);
    const float4 aa = a4[lane];
    const float4 ab = a4[lane + 64];
    const float4 ac = a4[lane + 128];

    float dot = aa.x*xa.x + aa.y*xa.y + aa.z*xa.z + aa.w*xa.w
              + ab.x*xb.x + ab.y*xb.y + ab.z*xb.z + ab.w*xb.w
              + ac.x*xc.x + ac.y*xc.y + ac.z*xc.z + ac.w*xc.w;
    float nx  = xa.x*xa.x + xa.y*xa.y + xa.z*xa.z + xa.w*xa.w
              + xb.x*xb.x + xb.y*xb.y + xb.z*xb.z + xb.w*xb.w
              + xc.x*xc.x + xc.y*xc.y + xc.z*xc.z + xc.w*xc.w;
    float asq = aa.x*aa.x + aa.y*aa.y + aa.z*aa.z + aa.w*aa.w
              + ab.x*ab.x + ab.y*ab.y + ab.z*ab.z + ab.w*ab.w
              + ac.x*ac.x + ac.y*ac.y + ac.z*ac.z + ac.w*ac.w;

    #pragma unroll
    for (int s = 32; s > 0; s >>= 1) {
        dot += __shfl_xor(dot, s);
        nx  += __shfl_xor(nx, s);
        asq += __shfl_xor(asq, s);
    }
    if (lane == 0)
        cosv[vid0] = dot / fmaxf(sqrtf(asq) * sqrtf(nx), EPS);
}

// ---------------- K2: offsets via LDS scan + pair hinges + mean -------------
__global__ __launch_bounds__(1024) void pairsum_kernel(
    const int* __restrict__ p_lens, const int* __restrict__ n_lens,
    const float* __restrict__ cosv, float* __restrict__ out, int P, int bs)
{
    __shared__ int sp[1024], sn[1024];
    __shared__ float sw[16];
    __shared__ int   si[16];
    const int tid = threadIdx.x;
    const int wave = tid >> 6;
    const int lane = tid & 63;

    const int p = (tid < bs) ? p_lens[tid] : 0;
    const int n = (tid < bs) ? n_lens[tid] : 0;
    sp[tid] = p; sn[tid] = n;
    __syncthreads();
    for (int off = 1; off < 1024; off <<= 1) {   // Hillis-Steele inclusive
        int vp = (tid >= off) ? sp[tid - off] : 0;
        int vn = (tid >= off) ? sn[tid - off] : 0;
        __syncthreads();
        sp[tid] += vp; sn[tid] += vn;
        __syncthreads();
    }

    float s = 0.0f;
    int   tp = 0;
    if (tid < bs) {
        const float* cp = cosv + (sp[tid] - p);       // exclusive offsets
        const float* cn = cosv + P + (sn[tid] - n);
        tp = p * n;
        for (int j = 0; j < p; ++j) {
            const float cap = cp[j];
            for (int k = 0; k < n; ++k)
                s += fmaxf(cn[k] - cap + 1.0f, 0.0f); // = d_ap - d_an + margin
        }
    }
    #pragma unroll
    for (int sh = 32; sh > 0; sh >>= 1) {
        s  += __shfl_xor(s, sh);
        tp += __shfl_xor(tp, sh);
    }
    if (lane == 0) { sw[wave] = s; si[wave] = tp; }
    __syncthreads();
    if (tid == 0) {
        float S = 0.0f; int T = 0;
        #pragma unroll
        for (int w = 0; w < 16; ++w) { S += sw[w]; T += si[w]; }
        *out = S / (float)T;
    }
}

extern "C" void kernel_launch(void* const* d_in, const int* in_sizes, int n_in,
                              void* d_out, int out_size, void* d_ws, size_t ws_size,
                              hipStream_t stream) {
    const float* anchor   = (const float*)d_in[0];
    const float* positive = (const float*)d_in[1];
    const float* negative = (const float*)d_in[2];
    const int*   p_lens   = (const int*)d_in[3];
    const int*   n_lens   = (const int*)d_in[4];
    float* out = (float*)d_out;

    const int bs = in_sizes[3];           // 1024
    const int P  = in_sizes[1] / DIM;     // total positive vectors
    const int N  = in_sizes[2] / DIM;     // total negative vectors

    float* cosv = (float*)d_ws;

    const int nvec = P + N;
    cosine_kernel<<<(nvec + 7) / 8, 512, 0, stream>>>(anchor, positive, negative,
                                                      p_lens, n_lens, cosv,
                                                      P, N, bs);
    pairsum_kernel<<<1, 1024, 0, stream>>>(p_lens, n_lens, cosv, out, P, bs);
}